// Round 6
// baseline (643.539 us; speedup 1.0000x reference)
//
#include <hip/hip_runtime.h>
#include <math.h>

#define HDIM 256
#define KDIM 16
#define SDIM 200
#define BDIM 512
#define NROWS (BDIM * SDIM)   // 102400
#define SPAD 208              // 6*32 + 16 padded rows per batch

typedef __bf16 bf16x8 __attribute__((ext_vector_type(8)));
typedef __bf16 bf16x4 __attribute__((ext_vector_type(4)));
typedef float  f32x4  __attribute__((ext_vector_type(4)));

// ---------------------------------------------------------------------------
// Fused pack: W1, W2, W3 -> fragment-ready split-bf16 layout
//   dst[((k>>3)*N + n)*8 + (k&7)] = hi/lo bf16 of W[k*N + n]
// ---------------------------------------------------------------------------
__global__ __launch_bounds__(256) void pack_all(
    const float* __restrict__ W1, const float* __restrict__ W2,
    const float* __restrict__ W3,
    __bf16* __restrict__ w1h, __bf16* __restrict__ w1l,
    __bf16* __restrict__ w2h, __bf16* __restrict__ w2l,
    __bf16* __restrict__ w3h, __bf16* __restrict__ w3l)
{
    int gid = blockIdx.x * 256 + threadIdx.x;
    const float* src;
    __bf16 *oh, *ol;
    int e, N;
    if (gid < 65536)       { src = W1; oh = w1h; ol = w1l; e = gid;          N = 256; }
    else if (gid < 131072) { src = W2; oh = w2h; ol = w2l; e = gid - 65536;  N = 256; }
    else if (gid < 135168) { src = W3; oh = w3h; ol = w3l; e = gid - 131072; N = 16;  }
    else return;

    int j  = e & 7;
    int n  = (e >> 3) & (N - 1);
    int kg = e >> 3; kg = (N == 256) ? (kg >> 8) : (kg >> 4);
    int k  = kg * 8 + j;
    float v = src[k * N + n];
    __bf16 h = (__bf16)v;
    oh[e] = h;
    ol[e] = (__bf16)(v - (float)h);
}

// ---------------------------------------------------------------------------
// stage ROWS rows of X (clamped to NROWS-1) -> LDS split-bf16, swizzled
// ---------------------------------------------------------------------------
template<int ROWS>
__device__ __forceinline__ void stage_x(
    const float* __restrict__ X, long r0, int tid,
    __bf16* __restrict__ Ahi, __bf16* __restrict__ Alo)
{
    const f32x4* Xg = (const f32x4*)X;
    #pragma unroll
    for (int t = 0; t < (ROWS * HDIM / 4) / 256; ++t) {
        int v4  = tid + t * 256;
        int row = v4 >> 6;                 // 64 f32x4 per row
        long grow = r0 + row;
        if (grow > (long)NROWS - 1) grow = (long)NROWS - 1;   // tail clamp
        f32x4 f = Xg[grow * 64 + (v4 & 63)];
        int col = (v4 & 63) << 2;
        int kgs = (col >> 3) ^ (row & 31);
        int base = row * HDIM + kgs * 8 + (col & 7);
        __bf16 h0 = (__bf16)f[0], h1 = (__bf16)f[1],
               h2 = (__bf16)f[2], h3 = (__bf16)f[3];
        bf16x4 hv = {h0, h1, h2, h3};
        bf16x4 lv = {(__bf16)(f[0] - (float)h0), (__bf16)(f[1] - (float)h1),
                     (__bf16)(f[2] - (float)h2), (__bf16)(f[3] - (float)h3)};
        *(bf16x4*)(&Ahi[base]) = hv;
        *(bf16x4*)(&Alo[base]) = lv;
    }
}

// ---------------------------------------------------------------------------
// One MLP layer on an MT*16-row LDS tile (v8 machinery, swapped-operand
// MFMA, split-bf16 3-pass). In-place: reads Ahi/Alo, writes relu(out).
// ---------------------------------------------------------------------------
template<int MT>
__device__ __forceinline__ void layer_t(
    const __bf16* __restrict__ Wh, const __bf16* __restrict__ Wl,
    const float* __restrict__ bias,
    __bf16* __restrict__ Ahi, __bf16* __restrict__ Alo,
    int w, int l15, int quad)
{
    f32x4 acc[MT][4];
    #pragma unroll
    for (int mt = 0; mt < MT; ++mt)
        #pragma unroll
        for (int nt = 0; nt < 4; ++nt)
            acc[mt][nt] = (f32x4){0.f, 0.f, 0.f, 0.f};

    #pragma unroll
    for (int kc = 0; kc < 8; ++kc) {
        bf16x8 bh[4], bl[4];
        #pragma unroll
        for (int nt = 0; nt < 4; ++nt) {
            int n  = w * 64 + nt * 16 + l15;
            int kg = kc * 4 + quad;
            bh[nt] = *(const bf16x8*)(Wh + (kg * HDIM + n) * 8);
            bl[nt] = *(const bf16x8*)(Wl + (kg * HDIM + n) * 8);
        }
        #pragma unroll
        for (int mt = 0; mt < MT; ++mt) {
            int row = mt * 16 + l15;
            int kgs = (kc * 4 + quad) ^ (row & 31);
            bf16x8 ah = *(const bf16x8*)(&Ahi[row * HDIM + kgs * 8]);
            bf16x8 al = *(const bf16x8*)(&Alo[row * HDIM + kgs * 8]);
            #pragma unroll
            for (int nt = 0; nt < 4; ++nt) {
                acc[mt][nt] = __builtin_amdgcn_mfma_f32_16x16x32_bf16(
                    bh[nt], ah, acc[mt][nt], 0, 0, 0);
                acc[mt][nt] = __builtin_amdgcn_mfma_f32_16x16x32_bf16(
                    bh[nt], al, acc[mt][nt], 0, 0, 0);
                acc[mt][nt] = __builtin_amdgcn_mfma_f32_16x16x32_bf16(
                    bl[nt], ah, acc[mt][nt], 0, 0, 0);
            }
        }
    }
    __syncthreads();   // everyone done reading A before overwrite

    // C layout (swapped): m = mt*16 + (lane&15), n = w*64 + nt*16 + quad*4 + r
    f32x4 bias4[4];
    #pragma unroll
    for (int nt = 0; nt < 4; ++nt)
        bias4[nt] = *(const f32x4*)(bias + w * 64 + nt * 16 + quad * 4);

    #pragma unroll
    for (int mt = 0; mt < MT; ++mt)
        #pragma unroll
        for (int nt = 0; nt < 4; ++nt) {
            int m   = mt * 16 + l15;
            int g   = w * 8 + nt * 2 + (quad >> 1);          // col>>3
            int idx = m * HDIM + (((g ^ (m & 31)) * 8) + (quad & 1) * 4);
            bf16x4 hv, lv;
            #pragma unroll
            for (int r = 0; r < 4; ++r) {
                float v = fmaxf(acc[mt][nt][r] + bias4[nt][r], 0.f);
                __bf16 h = (__bf16)v;
                hv[r] = h;
                lv[r] = (__bf16)(v - (float)h);
            }
            *(bf16x4*)(&Ahi[idx]) = hv;
            *(bf16x4*)(&Alo[idx]) = lv;
        }
    __syncthreads();
}

// ---------------------------------------------------------------------------
// Fused kernel: one block per batch b. 6x32-row chunks + 16-row tail run
// the v8 MLP+logits+k-softmax, writing logits into LDS D[208][16] (no
// global P). Then in-LDS column softmax over s + tf/invk scale, then the
// final aggregation out[b,k,h] = sum_s X[s,h]*D[s,k] with 4 waves owning
// 4 k-columns each (no cross-wave reduce). Grid 512 = 2 blocks/CU, all
// resident.
// ---------------------------------------------------------------------------
__global__ __launch_bounds__(256) void fused_kernel(
    const float* __restrict__ X, const int* __restrict__ mask,
    const float* __restrict__ tf,
    const __bf16* __restrict__ W1h, const __bf16* __restrict__ W1l,
    const float* __restrict__ b1,
    const __bf16* __restrict__ W2h, const __bf16* __restrict__ W2l,
    const float* __restrict__ b2,
    const __bf16* __restrict__ W3h, const __bf16* __restrict__ W3l,
    float* __restrict__ out)
{
    __shared__ __bf16 Ahi[32 * HDIM];      // 16 KB
    __shared__ __bf16 Alo[32 * HDIM];      // 16 KB
    __shared__ float  Dl[SPAD * KDIM];     // 13 KB logits -> weights
    __shared__ float  part[256];           // 1 KB colsum partials
    __shared__ float  tfl[SDIM];
    __shared__ float  invk[KDIM];

    const int tid  = threadIdx.x;
    const int lane = tid & 63;
    const int w    = tid >> 6;
    const int l15  = lane & 15;
    const int quad = lane >> 4;
    const int b    = blockIdx.x;
    const long rb  = (long)b * SDIM;

    // ================= MLP + logits + k-softmax, chunked =================
    #pragma unroll 1
    for (int c = 0; c < 6; ++c) {
        stage_x<32>(X, rb + c * 32, tid, Ahi, Alo);
        __syncthreads();
        layer_t<2>(W1h, W1l, b1, Ahi, Alo, w, l15, quad);
        layer_t<2>(W2h, W2l, b2, Ahi, Alo, w, l15, quad);

        if (w < 2) {
            f32x4 lg = {0.f, 0.f, 0.f, 0.f};
            #pragma unroll
            for (int kc = 0; kc < 8; ++kc) {
                int row = w * 16 + l15;
                int kg  = kc * 4 + quad;
                int kgs = kg ^ (row & 31);
                bf16x8 ah = *(const bf16x8*)(&Ahi[row * HDIM + kgs * 8]);
                bf16x8 al = *(const bf16x8*)(&Alo[row * HDIM + kgs * 8]);
                bf16x8 bh = *(const bf16x8*)(W3h + (kg * KDIM + l15) * 8);
                bf16x8 bl = *(const bf16x8*)(W3l + (kg * KDIM + l15) * 8);
                lg = __builtin_amdgcn_mfma_f32_16x16x32_bf16(ah, bh, lg, 0, 0, 0);
                lg = __builtin_amdgcn_mfma_f32_16x16x32_bf16(al, bh, lg, 0, 0, 0);
                lg = __builtin_amdgcn_mfma_f32_16x16x32_bf16(ah, bl, lg, 0, 0, 0);
            }
            #pragma unroll
            for (int r = 0; r < 4; ++r) {
                float v  = lg[r];
                float mx = v;
                mx = fmaxf(mx, __shfl_xor(mx, 1));
                mx = fmaxf(mx, __shfl_xor(mx, 2));
                mx = fmaxf(mx, __shfl_xor(mx, 4));
                mx = fmaxf(mx, __shfl_xor(mx, 8));
                float e = __expf(v - mx);
                float s = e;
                s += __shfl_xor(s, 1);
                s += __shfl_xor(s, 2);
                s += __shfl_xor(s, 4);
                s += __shfl_xor(s, 8);
                int local = c * 32 + w * 16 + quad * 4 + r;
                int mv = mask[rb + local];        // local < 192 here
                Dl[local * KDIM + l15] = mv ? (e / s) * 0.25f : -2500.0f;
            }
        }
        __syncthreads();   // D written; Ahi free for next chunk
    }

    // ---- 16-row tail (rows 192..207; 200..207 forced to -2500) ----
    {
        stage_x<16>(X, rb + 192, tid, Ahi, Alo);
        __syncthreads();
        layer_t<1>(W1h, W1l, b1, Ahi, Alo, w, l15, quad);
        layer_t<1>(W2h, W2l, b2, Ahi, Alo, w, l15, quad);

        if (w == 0) {
            f32x4 lg = {0.f, 0.f, 0.f, 0.f};
            #pragma unroll
            for (int kc = 0; kc < 8; ++kc) {
                int row = l15;
                int kg  = kc * 4 + quad;
                int kgs = kg ^ (row & 31);
                bf16x8 ah = *(const bf16x8*)(&Ahi[row * HDIM + kgs * 8]);
                bf16x8 al = *(const bf16x8*)(&Alo[row * HDIM + kgs * 8]);
                bf16x8 bh = *(const bf16x8*)(W3h + (kg * KDIM + l15) * 8);
                bf16x8 bl = *(const bf16x8*)(W3l + (kg * KDIM + l15) * 8);
                lg = __builtin_amdgcn_mfma_f32_16x16x32_bf16(ah, bh, lg, 0, 0, 0);
                lg = __builtin_amdgcn_mfma_f32_16x16x32_bf16(al, bh, lg, 0, 0, 0);
                lg = __builtin_amdgcn_mfma_f32_16x16x32_bf16(ah, bl, lg, 0, 0, 0);
            }
            #pragma unroll
            for (int r = 0; r < 4; ++r) {
                float v  = lg[r];
                float mx = v;
                mx = fmaxf(mx, __shfl_xor(mx, 1));
                mx = fmaxf(mx, __shfl_xor(mx, 2));
                mx = fmaxf(mx, __shfl_xor(mx, 4));
                mx = fmaxf(mx, __shfl_xor(mx, 8));
                float e = __expf(v - mx);
                float s = e;
                s += __shfl_xor(s, 1);
                s += __shfl_xor(s, 2);
                s += __shfl_xor(s, 4);
                s += __shfl_xor(s, 8);
                int local = 192 + quad * 4 + r;
                int mv = (local < SDIM) ? mask[rb + local] : 0;
                Dl[local * KDIM + l15] = mv ? (e / s) * 0.25f : -2500.0f;
            }
        }
        __syncthreads();
    }

    // ================= column softmax over s + tf/invk scale =============
    {
        const int k = tid & 15, rg = tid >> 4;    // 16 threads per column
        float ps = 0.f;
        #pragma unroll
        for (int i = 0; i < SPAD / 16; ++i) {     // 13 rows per thread
            int s = rg + i * 16;
            float e = __expf(Dl[s * KDIM + k]);   // exp(-2500) == 0
            Dl[s * KDIM + k] = e;
            ps += e;
        }
        part[tid] = ps;
        if (tid < SDIM) tfl[tid] = tf[rb + tid];
        __syncthreads();

        if (tid < KDIM) {
            float s = 0.f;
            #pragma unroll
            for (int g = 0; g < 16; ++g) s += part[tid + g * 16];
            invk[tid] = 1.f / s;
        }
        __syncthreads();

        #pragma unroll
        for (int i = 0; i < SPAD / 16; ++i) {
            int s = rg + i * 16;
            float t = (s < SDIM) ? tfl[s] : 0.f;
            Dl[s * KDIM + k] *= t * invk[k];
        }
        __syncthreads();
    }

    // ================= aggregation: out[b,k,h] = sum_s X[s,h]*D[s,k] =====
    {
        f32x4 a4[4];
        #pragma unroll
        for (int j = 0; j < 4; ++j) a4[j] = (f32x4){0.f, 0.f, 0.f, 0.f};

        const f32x4* Xb4 = (const f32x4*)(X + rb * HDIM);
        const int soff = w * 50;                  // stagger waves over s
        #pragma unroll 5
        for (int si = 0; si < SDIM; ++si) {
            int s = si + soff;
            if (s >= SDIM) s -= SDIM;
            f32x4 x = Xb4[s * 64 + lane];         // 1KB coalesced per wave
            f32x4 d = *(const f32x4*)(&Dl[s * KDIM + w * 4]);  // uniform 16B
            #pragma unroll
            for (int j = 0; j < 4; ++j) a4[j] += x * d[j];     // k = 4w+j
        }

        float* ob = out + ((long)b * KDIM + w * 4) * HDIM;
        #pragma unroll
        for (int j = 0; j < 4; ++j)
            *(f32x4*)(ob + j * HDIM + 4 * lane) = a4[j];
    }
}

extern "C" void kernel_launch(void* const* d_in, const int* in_sizes, int n_in,
                              void* d_out, int out_size, void* d_ws, size_t ws_size,
                              hipStream_t stream) {
    (void)in_sizes; (void)n_in; (void)out_size; (void)ws_size;
    const float* X    = (const float*)d_in[0];
    const int*   mask = (const int*)  d_in[1];
    const float* tf   = (const float*)d_in[2];
    const float* W1   = (const float*)d_in[3];
    const float* b1   = (const float*)d_in[4];
    const float* W2   = (const float*)d_in[5];
    const float* b2   = (const float*)d_in[6];
    const float* W3   = (const float*)d_in[7];
    float* out = (float*)d_out;

    char* ws = (char*)d_ws;
    __bf16* w1h = (__bf16*)ws;                         // 65536 elems each
    __bf16* w1l = w1h + 65536;
    __bf16* w2h = w1l + 65536;
    __bf16* w2l = w2h + 65536;
    __bf16* w3h = w2l + 65536;                         // 4096 elems each
    __bf16* w3l = w3h + 4096;

    pack_all<<<528, 256, 0, stream>>>(W1, W2, W3, w1h, w1l, w2h, w2l, w3h, w3l);
    fused_kernel<<<BDIM, 256, 0, stream>>>(X, mask, tf, w1h, w1l, b1,
                                           w2h, w2l, b2, w3h, w3l, out);
}

// Round 7
// 256.186 us; speedup vs baseline: 2.5120x; 2.5120x over previous
//
#include <hip/hip_runtime.h>
#include <math.h>

#define HDIM 256
#define KDIM 16
#define SDIM 200
#define BDIM 512
#define NROWS (BDIM * SDIM)   // 102400
#define TM 32                 // rows per block in kernel 1 (32KB LDS)

typedef __bf16 bf16x8 __attribute__((ext_vector_type(8)));
typedef __bf16 bf16x4 __attribute__((ext_vector_type(4)));
typedef float  f32x4  __attribute__((ext_vector_type(4)));

// ---------------------------------------------------------------------------
// Fused pack: W1, W2, W3 -> fragment-ready split-bf16 layout
//   dst[((k>>3)*N + n)*8 + (k&7)] = hi/lo bf16 of W[k*N + n]
// ---------------------------------------------------------------------------
__global__ __launch_bounds__(256) void pack_all(
    const float* __restrict__ W1, const float* __restrict__ W2,
    const float* __restrict__ W3,
    __bf16* __restrict__ w1h, __bf16* __restrict__ w1l,
    __bf16* __restrict__ w2h, __bf16* __restrict__ w2l,
    __bf16* __restrict__ w3h, __bf16* __restrict__ w3l)
{
    int gid = blockIdx.x * 256 + threadIdx.x;
    const float* src;
    __bf16 *oh, *ol;
    int e, N;
    if (gid < 65536)       { src = W1; oh = w1h; ol = w1l; e = gid;          N = 256; }
    else if (gid < 131072) { src = W2; oh = w2h; ol = w2l; e = gid - 65536;  N = 256; }
    else if (gid < 135168) { src = W3; oh = w3h; ol = w3l; e = gid - 131072; N = 16;  }
    else return;

    int j  = e & 7;
    int n  = (e >> 3) & (N - 1);
    int kg = e >> 3; kg = (N == 256) ? (kg >> 8) : (kg >> 4);
    int k  = kg * 8 + j;
    float v = src[k * N + n];
    __bf16 h = (__bf16)v;
    oh[e] = h;
    ol[e] = (__bf16)(v - (float)h);
}

// ---------------------------------------------------------------------------
// Kernel 1 v12: 8-WAVE BLOCKS (512 threads), TM=32. Same math as v8
// (bit-identical), but each wave owns a 32-col n-slice (nt<2, acc[2][2],
// 4 W-loads/kc). Rationale: v8's counters show all pipes ~1/3 busy and
// ~6 ACTIVE waves/CU (OccupancyPercent 19%) -- active-wave starvation.
// 8-wave blocks double the independent waves interleaving per block and
// drop per-wave VGPR, raising the resident/active ceiling (20 -> ~28).
// ---------------------------------------------------------------------------
__global__ __launch_bounds__(512) void mlp_softk_mfma(
    const float* __restrict__ X, const int* __restrict__ mask,
    const __bf16* __restrict__ W1h, const __bf16* __restrict__ W1l,
    const float* __restrict__ b1,
    const __bf16* __restrict__ W2h, const __bf16* __restrict__ W2l,
    const float* __restrict__ b2,
    const __bf16* __restrict__ W3h, const __bf16* __restrict__ W3l,
    float* __restrict__ P)
{
    __shared__ __bf16 Ahi[TM * HDIM];   // 16 KB
    __shared__ __bf16 Alo[TM * HDIM];   // 16 KB

    const int tid  = threadIdx.x;
    const int lane = tid & 63;
    const int w    = tid >> 6;      // wave id 0..7: owns cols 32w..32w+31
    const int l15  = lane & 15;
    const int quad = lane >> 4;
    const long r0  = (long)blockIdx.x * TM;

    // ---- stage X tile -> LDS as split bf16 (swizzled) ----
    {
        const float4* Xt = (const float4*)(X + r0 * HDIM);
        #pragma unroll
        for (int t = 0; t < (TM * HDIM / 4) / 512; ++t) {
            int v4  = tid + t * 512;
            float4 f = Xt[v4];
            int row = v4 >> 6;            // 64 float4 per row
            int col = (v4 & 63) << 2;
            int kgs = (col >> 3) ^ (row & 31);
            int base = row * HDIM + kgs * 8 + (col & 7);
            __bf16 h0 = (__bf16)f.x, h1 = (__bf16)f.y,
                   h2 = (__bf16)f.z, h3 = (__bf16)f.w;
            bf16x4 hv = {h0, h1, h2, h3};
            bf16x4 lv = {(__bf16)(f.x - (float)h0), (__bf16)(f.y - (float)h1),
                         (__bf16)(f.z - (float)h2), (__bf16)(f.w - (float)h3)};
            *(bf16x4*)(&Ahi[base]) = hv;
            *(bf16x4*)(&Alo[base]) = lv;
        }
    }
    __syncthreads();

    f32x4 acc[2][2];

    auto layer = [&](const __bf16* __restrict__ Wh, const __bf16* __restrict__ Wl,
                     const float* __restrict__ bias) {
        #pragma unroll
        for (int mt = 0; mt < 2; ++mt)
            #pragma unroll
            for (int nt = 0; nt < 2; ++nt)
                acc[mt][nt] = (f32x4){0.f, 0.f, 0.f, 0.f};

        #pragma unroll
        for (int kc = 0; kc < 8; ++kc) {
            bf16x8 bh[2], bl[2], ah[2], al[2];
            #pragma unroll
            for (int nt = 0; nt < 2; ++nt) {
                int n  = w * 32 + nt * 16 + l15;
                int kg = kc * 4 + quad;
                bh[nt] = *(const bf16x8*)(Wh + (kg * HDIM + n) * 8);
                bl[nt] = *(const bf16x8*)(Wl + (kg * HDIM + n) * 8);
            }
            #pragma unroll
            for (int mt = 0; mt < 2; ++mt) {
                int row = mt * 16 + l15;
                int kgs = (kc * 4 + quad) ^ (row & 31);
                ah[mt] = *(const bf16x8*)(&Ahi[row * HDIM + kgs * 8]);
                al[mt] = *(const bf16x8*)(&Alo[row * HDIM + kgs * 8]);
            }
            // SWAPPED: A-operand = W fragment, B-operand = X fragment.
            #pragma unroll
            for (int mt = 0; mt < 2; ++mt)
                #pragma unroll
                for (int nt = 0; nt < 2; ++nt) {
                    acc[mt][nt] = __builtin_amdgcn_mfma_f32_16x16x32_bf16(
                        bh[nt], ah[mt], acc[mt][nt], 0, 0, 0);
                    acc[mt][nt] = __builtin_amdgcn_mfma_f32_16x16x32_bf16(
                        bh[nt], al[mt], acc[mt][nt], 0, 0, 0);
                    acc[mt][nt] = __builtin_amdgcn_mfma_f32_16x16x32_bf16(
                        bl[nt], ah[mt], acc[mt][nt], 0, 0, 0);
                }
        }
        __syncthreads();   // everyone done reading A before overwrite

        // C layout (swapped): m = mt*16 + (lane&15), n = w*32 + nt*16 + quad*4 + r
        // -> regs r=0..3 are 4 consecutive h-columns: one bf16x4 write per array.
        f32x4 bias4[2];
        #pragma unroll
        for (int nt = 0; nt < 2; ++nt)
            bias4[nt] = *(const f32x4*)(bias + w * 32 + nt * 16 + quad * 4);

        #pragma unroll
        for (int mt = 0; mt < 2; ++mt)
            #pragma unroll
            for (int nt = 0; nt < 2; ++nt) {
                int m   = mt * 16 + l15;
                int g   = w * 4 + nt * 2 + (quad >> 1);          // n>>3
                int idx = m * HDIM + (((g ^ (m & 31)) * 8) + (quad & 1) * 4);
                bf16x4 hv, lv;
                #pragma unroll
                for (int r = 0; r < 4; ++r) {
                    float v = fmaxf(acc[mt][nt][r] + bias4[nt][r], 0.f);
                    __bf16 h = (__bf16)v;
                    hv[r] = h;
                    lv[r] = (__bf16)(v - (float)h);
                }
                *(bf16x4*)(&Ahi[idx]) = hv;
                *(bf16x4*)(&Alo[idx]) = lv;
            }
        __syncthreads();
    };

    layer(W1h, W1l, b1);
    layer(W2h, W2l, b2);

    // ---- logits: waves 0,1 each handle one 16-row m-tile (TM=32) ----
    // (unswapped: want k across lanes for the shfl_xor softmax)
    if (w < 2) {
        f32x4 lg = {0.f, 0.f, 0.f, 0.f};
        #pragma unroll
        for (int kc = 0; kc < 8; ++kc) {
            int row = w * 16 + l15;
            int kg  = kc * 4 + quad;
            int kgs = kg ^ (row & 31);
            bf16x8 ah = *(const bf16x8*)(&Ahi[row * HDIM + kgs * 8]);
            bf16x8 al = *(const bf16x8*)(&Alo[row * HDIM + kgs * 8]);
            bf16x8 bh = *(const bf16x8*)(W3h + (kg * KDIM + l15) * 8);
            bf16x8 bl = *(const bf16x8*)(W3l + (kg * KDIM + l15) * 8);
            lg = __builtin_amdgcn_mfma_f32_16x16x32_bf16(ah, bh, lg, 0, 0, 0);
            lg = __builtin_amdgcn_mfma_f32_16x16x32_bf16(al, bh, lg, 0, 0, 0);
            lg = __builtin_amdgcn_mfma_f32_16x16x32_bf16(ah, bl, lg, 0, 0, 0);
        }

        // softmax over k: 16 lanes of a quad-group hold the 16 cols of a row
        #pragma unroll
        for (int r = 0; r < 4; ++r) {
            float v  = lg[r];
            float mx = v;
            mx = fmaxf(mx, __shfl_xor(mx, 1));
            mx = fmaxf(mx, __shfl_xor(mx, 2));
            mx = fmaxf(mx, __shfl_xor(mx, 4));
            mx = fmaxf(mx, __shfl_xor(mx, 8));
            float e = __expf(v - mx);
            float s = e;
            s += __shfl_xor(s, 1);
            s += __shfl_xor(s, 2);
            s += __shfl_xor(s, 4);
            s += __shfl_xor(s, 8);
            int grow = (int)r0 + w * 16 + quad * 4 + r;
            int mv   = mask[grow];
            float ov = mv ? (e / s) * 0.25f : -2500.0f;   // (-10000)/sqrt(16)
            P[(long)grow * KDIM + l15] = ov;
        }
    }
}

// ---------------------------------------------------------------------------
// Kernel 2 (UNCHANGED): 512 threads = 8 waves = (s-quarter sq, k-half kh).
// ---------------------------------------------------------------------------
__global__ __launch_bounds__(512) void softs_agg_kernel(
    const float* __restrict__ X, const float* __restrict__ tf,
    const float* __restrict__ P, float* __restrict__ out)
{
    __shared__ float wl[SDIM * KDIM];          // 12.8 KB
    __shared__ float tfl[SDIM];                // 0.8 KB
    __shared__ float invk[KDIM];
    __shared__ float red[6 * 8 * HDIM];        // 48 KB: slot (sq-1)*2+kh
    float* psum = red;                         // alias (dead before red use)

    const int tid = threadIdx.x;
    const int b   = blockIdx.x;

    // ---- phase 1: column softmax over S (exp(-2500)==0 handles the mask) ----
    const float* Pb = P + (long)b * SDIM * KDIM;
    float ps = 0.f;
    #pragma unroll
    for (int t = 0; t < 7; ++t) {
        int i = tid + t * 512;
        if (i < SDIM * KDIM) {
            float e = __expf(Pb[i]);
            wl[i] = e;
            ps += e;
        }
    }
    psum[tid] = ps;
    if (tid < SDIM) tfl[tid] = tf[b * SDIM + tid];
    __syncthreads();

    if (tid < KDIM) {
        float s = 0.f;
        #pragma unroll
        for (int g = 0; g < 32; ++g) s += psum[tid + g * 16];   // 512%16==0
        invk[tid] = 1.f / s;
    }
    __syncthreads();

    #pragma unroll
    for (int t = 0; t < 7; ++t) {
        int i = tid + t * 512;
        if (i < SDIM * KDIM) wl[i] *= tfl[i >> 4] * invk[i & 15];
    }
    __syncthreads();

    // ---- phase 2: out[b,k,h] = sum_s X[b,s,h] * wl[s,k] ----
    const int wv = tid >> 6;
    const int sq = wv >> 1;      // s-quarter: [50*sq, 50*sq+50)
    const int kh = wv & 1;       // k-half: k in [8*kh, 8*kh+8)
    const int ln = tid & 63;     // lane -> h-cols 4*ln..4*ln+3

    f32x4 acc[8];
    #pragma unroll
    for (int j = 0; j < 8; ++j) acc[j] = (f32x4){0.f, 0.f, 0.f, 0.f};

    const f32x4* Xb4 = (const f32x4*)(X + (long)b * SDIM * HDIM);
    const f32x4* wl4 = (const f32x4*)wl;
    const int s0 = sq * 50;
    #pragma unroll 5
    for (int si = 0; si < 50; ++si) {
        int s = s0 + si;
        f32x4 x  = Xb4[s * 64 + ln];             // 1KB coalesced per wave
        f32x4 d0 = wl4[s * 4 + 2 * kh + 0];      // wave-uniform LDS b128
        f32x4 d1 = wl4[s * 4 + 2 * kh + 1];
        #pragma unroll
        for (int j = 0; j < 4; ++j) {
            acc[j]     += x * d0[j];             // k = 8kh + j
            acc[4 + j] += x * d1[j];             // k = 8kh + 4 + j
        }
    }

    // ---- tree reduce over s-quarters: sq>0 deposit, sq==0 sums + stores ----
    if (sq > 0) {
        float* rp = red + (((sq - 1) * 2 + kh) * 8) * HDIM;
        #pragma unroll
        for (int j = 0; j < 8; ++j)
            *(f32x4*)(rp + j * HDIM + 4 * ln) = acc[j];
    }
    __syncthreads();
    if (sq == 0) {
        #pragma unroll
        for (int p = 0; p < 3; ++p) {
            const float* rp = red + ((p * 2 + kh) * 8) * HDIM;
            #pragma unroll
            for (int j = 0; j < 8; ++j)
                acc[j] += *(const f32x4*)(rp + j * HDIM + 4 * ln);
        }
        float* ob = out + (long)b * KDIM * HDIM + kh * 8 * HDIM;
        #pragma unroll
        for (int j = 0; j < 8; ++j)
            *(f32x4*)(ob + j * HDIM + 4 * ln) = acc[j];
    }
}

extern "C" void kernel_launch(void* const* d_in, const int* in_sizes, int n_in,
                              void* d_out, int out_size, void* d_ws, size_t ws_size,
                              hipStream_t stream) {
    (void)in_sizes; (void)n_in; (void)out_size; (void)ws_size;
    const float* X    = (const float*)d_in[0];
    const int*   mask = (const int*)  d_in[1];
    const float* tf   = (const float*)d_in[2];
    const float* W1   = (const float*)d_in[3];
    const float* b1   = (const float*)d_in[4];
    const float* W2   = (const float*)d_in[5];
    const float* b2   = (const float*)d_in[6];
    const float* W3   = (const float*)d_in[7];
    float* out = (float*)d_out;

    char* ws = (char*)d_ws;
    float*  P   = (float*)ws;                          // 102400*16*4 = 6,553,600 B
    __bf16* w1h = (__bf16*)(ws + 6553600);             // 65536 elems each
    __bf16* w1l = w1h + 65536;
    __bf16* w2h = w1l + 65536;
    __bf16* w2l = w2h + 65536;
    __bf16* w3h = w2l + 65536;                         // 4096 elems each
    __bf16* w3l = w3h + 4096;

    pack_all<<<528, 256, 0, stream>>>(W1, W2, W3, w1h, w1l, w2h, w2l, w3h, w3l);
    mlp_softk_mfma<<<NROWS / TM, 512, 0, stream>>>(X, mask, w1h, w1l, b1,
                                                   w2h, w2l, b2, w3h, w3l, P);
    softs_agg_kernel<<<BDIM, 512, 0, stream>>>(X, tf, P, out);
}

// Round 8
// 246.175 us; speedup vs baseline: 2.6142x; 1.0407x over previous
//
#include <hip/hip_runtime.h>
#include <math.h>

#define HDIM 256
#define KDIM 16
#define SDIM 200
#define BDIM 512
#define NROWS (BDIM * SDIM)   // 102400
#define TM 64                 // rows per block (64KB LDS, 2 blk/CU, 8 waves)

typedef __bf16 bf16x8 __attribute__((ext_vector_type(8)));
typedef __bf16 bf16x4 __attribute__((ext_vector_type(4)));
typedef float  f32x4  __attribute__((ext_vector_type(4)));

// ---------------------------------------------------------------------------
// Fused pack: W1, W2, W3 -> fragment-ready split-bf16 layout
//   dst[((k>>3)*N + n)*8 + (k&7)] = hi/lo bf16 of W[k*N + n]
// ---------------------------------------------------------------------------
__global__ __launch_bounds__(256) void pack_all(
    const float* __restrict__ W1, const float* __restrict__ W2,
    const float* __restrict__ W3,
    __bf16* __restrict__ w1h, __bf16* __restrict__ w1l,
    __bf16* __restrict__ w2h, __bf16* __restrict__ w2l,
    __bf16* __restrict__ w3h, __bf16* __restrict__ w3l)
{
    int gid = blockIdx.x * 256 + threadIdx.x;
    const float* src;
    __bf16 *oh, *ol;
    int e, N;
    if (gid < 65536)       { src = W1; oh = w1h; ol = w1l; e = gid;          N = 256; }
    else if (gid < 131072) { src = W2; oh = w2h; ol = w2l; e = gid - 65536;  N = 256; }
    else if (gid < 135168) { src = W3; oh = w3h; ol = w3l; e = gid - 131072; N = 16;  }
    else return;

    int j  = e & 7;
    int n  = (e >> 3) & (N - 1);
    int kg = e >> 3; kg = (N == 256) ? (kg >> 8) : (kg >> 4);
    int k  = kg * 8 + j;
    float v = src[k * N + n];
    __bf16 h = (__bf16)v;
    oh[e] = h;
    ol[e] = (__bf16)(v - (float)h);
}

// ---------------------------------------------------------------------------
// Kernel 1 v13: TM=64 x 8-wave blocks. v12 showed occupancy 19->35% but
// dur only -11%: the W-fragment vmem stream (512KB/block from L2, ~42us
// of per-CU vmem service at TM=32) is the serial upstream term, not MFMA.
// TM=64 halves it (0.8GB total) WITHOUT the round-3 confound (v9 had
// 4-wave/64-VGPR-acc blocks -> 8 waves/CU; here 8 waves x acc[4][2]=32
// VGPR, 2 blk/CU = 16-wave ceiling). mt 2->4: 24 MFMA per 4 loads per kc.
// Numerics bit-identical to v8/v12.
// ---------------------------------------------------------------------------
__global__ __launch_bounds__(512) void mlp_softk_mfma(
    const float* __restrict__ X, const int* __restrict__ mask,
    const __bf16* __restrict__ W1h, const __bf16* __restrict__ W1l,
    const float* __restrict__ b1,
    const __bf16* __restrict__ W2h, const __bf16* __restrict__ W2l,
    const float* __restrict__ b2,
    const __bf16* __restrict__ W3h, const __bf16* __restrict__ W3l,
    float* __restrict__ P)
{
    __shared__ __bf16 Ahi[TM * HDIM];   // 32 KB
    __shared__ __bf16 Alo[TM * HDIM];   // 32 KB

    const int tid  = threadIdx.x;
    const int lane = tid & 63;
    const int w    = tid >> 6;      // wave id 0..7: owns cols 32w..32w+31
    const int l15  = lane & 15;
    const int quad = lane >> 4;
    const long r0  = (long)blockIdx.x * TM;

    // ---- stage X tile -> LDS as split bf16 (swizzled) ----
    {
        const float4* Xt = (const float4*)(X + r0 * HDIM);
        #pragma unroll
        for (int t = 0; t < (TM * HDIM / 4) / 512; ++t) {
            int v4  = tid + t * 512;
            float4 f = Xt[v4];
            int row = v4 >> 6;            // 64 float4 per row
            int col = (v4 & 63) << 2;
            int kgs = (col >> 3) ^ (row & 31);
            int base = row * HDIM + kgs * 8 + (col & 7);
            __bf16 h0 = (__bf16)f.x, h1 = (__bf16)f.y,
                   h2 = (__bf16)f.z, h3 = (__bf16)f.w;
            bf16x4 hv = {h0, h1, h2, h3};
            bf16x4 lv = {(__bf16)(f.x - (float)h0), (__bf16)(f.y - (float)h1),
                         (__bf16)(f.z - (float)h2), (__bf16)(f.w - (float)h3)};
            *(bf16x4*)(&Ahi[base]) = hv;
            *(bf16x4*)(&Alo[base]) = lv;
        }
    }
    __syncthreads();

    f32x4 acc[4][2];

    auto layer = [&](const __bf16* __restrict__ Wh, const __bf16* __restrict__ Wl,
                     const float* __restrict__ bias) {
        #pragma unroll
        for (int mt = 0; mt < 4; ++mt)
            #pragma unroll
            for (int nt = 0; nt < 2; ++nt)
                acc[mt][nt] = (f32x4){0.f, 0.f, 0.f, 0.f};

        #pragma unroll
        for (int kc = 0; kc < 8; ++kc) {
            bf16x8 bh[2], bl[2];
            #pragma unroll
            for (int nt = 0; nt < 2; ++nt) {
                int n  = w * 32 + nt * 16 + l15;
                int kg = kc * 4 + quad;
                bh[nt] = *(const bf16x8*)(Wh + (kg * HDIM + n) * 8);
                bl[nt] = *(const bf16x8*)(Wl + (kg * HDIM + n) * 8);
            }
            #pragma unroll
            for (int mt = 0; mt < 4; ++mt) {
                int row = mt * 16 + l15;
                int kgs = (kc * 4 + quad) ^ (row & 31);
                bf16x8 ah = *(const bf16x8*)(&Ahi[row * HDIM + kgs * 8]);
                bf16x8 al = *(const bf16x8*)(&Alo[row * HDIM + kgs * 8]);
                // SWAPPED: A-operand = W fragment, B-operand = X fragment.
                #pragma unroll
                for (int nt = 0; nt < 2; ++nt) {
                    acc[mt][nt] = __builtin_amdgcn_mfma_f32_16x16x32_bf16(
                        bh[nt], ah, acc[mt][nt], 0, 0, 0);
                    acc[mt][nt] = __builtin_amdgcn_mfma_f32_16x16x32_bf16(
                        bh[nt], al, acc[mt][nt], 0, 0, 0);
                    acc[mt][nt] = __builtin_amdgcn_mfma_f32_16x16x32_bf16(
                        bl[nt], ah, acc[mt][nt], 0, 0, 0);
                }
            }
        }
        __syncthreads();   // everyone done reading A before overwrite

        // C layout (swapped): m = mt*16 + (lane&15), n = w*32 + nt*16 + quad*4 + r
        // -> regs r=0..3 are 4 consecutive h-columns: one bf16x4 write per array.
        f32x4 bias4[2];
        #pragma unroll
        for (int nt = 0; nt < 2; ++nt)
            bias4[nt] = *(const f32x4*)(bias + w * 32 + nt * 16 + quad * 4);

        #pragma unroll
        for (int mt = 0; mt < 4; ++mt)
            #pragma unroll
            for (int nt = 0; nt < 2; ++nt) {
                int m   = mt * 16 + l15;
                int g   = w * 4 + nt * 2 + (quad >> 1);          // n>>3
                int idx = m * HDIM + (((g ^ (m & 31)) * 8) + (quad & 1) * 4);
                bf16x4 hv, lv;
                #pragma unroll
                for (int r = 0; r < 4; ++r) {
                    float v = fmaxf(acc[mt][nt][r] + bias4[nt][r], 0.f);
                    __bf16 h = (__bf16)v;
                    hv[r] = h;
                    lv[r] = (__bf16)(v - (float)h);
                }
                *(bf16x4*)(&Ahi[idx]) = hv;
                *(bf16x4*)(&Alo[idx]) = lv;
            }
        __syncthreads();
    };

    layer(W1h, W1l, b1);
    layer(W2h, W2l, b2);

    // ---- logits: waves 0..3 each handle one 16-row m-tile (TM=64) ----
    // (unswapped: want k across lanes for the shfl_xor softmax)
    if (w < 4) {
        f32x4 lg = {0.f, 0.f, 0.f, 0.f};
        #pragma unroll
        for (int kc = 0; kc < 8; ++kc) {
            int row = w * 16 + l15;
            int kg  = kc * 4 + quad;
            int kgs = kg ^ (row & 31);
            bf16x8 ah = *(const bf16x8*)(&Ahi[row * HDIM + kgs * 8]);
            bf16x8 al = *(const bf16x8*)(&Alo[row * HDIM + kgs * 8]);
            bf16x8 bh = *(const bf16x8*)(W3h + (kg * KDIM + l15) * 8);
            bf16x8 bl = *(const bf16x8*)(W3l + (kg * KDIM + l15) * 8);
            lg = __builtin_amdgcn_mfma_f32_16x16x32_bf16(ah, bh, lg, 0, 0, 0);
            lg = __builtin_amdgcn_mfma_f32_16x16x32_bf16(al, bh, lg, 0, 0, 0);
            lg = __builtin_amdgcn_mfma_f32_16x16x32_bf16(ah, bl, lg, 0, 0, 0);
        }

        // softmax over k: 16 lanes of a quad-group hold the 16 cols of a row
        #pragma unroll
        for (int r = 0; r < 4; ++r) {
            float v  = lg[r];
            float mx = v;
            mx = fmaxf(mx, __shfl_xor(mx, 1));
            mx = fmaxf(mx, __shfl_xor(mx, 2));
            mx = fmaxf(mx, __shfl_xor(mx, 4));
            mx = fmaxf(mx, __shfl_xor(mx, 8));
            float e = __expf(v - mx);
            float s = e;
            s += __shfl_xor(s, 1);
            s += __shfl_xor(s, 2);
            s += __shfl_xor(s, 4);
            s += __shfl_xor(s, 8);
            int grow = (int)r0 + w * 16 + quad * 4 + r;
            int mv   = mask[grow];
            float ov = mv ? (e / s) * 0.25f : -2500.0f;   // (-10000)/sqrt(16)
            P[(long)grow * KDIM + l15] = ov;
        }
    }
}

// ---------------------------------------------------------------------------
// Kernel 2 (UNCHANGED): 512 threads = 8 waves = (s-quarter sq, k-half kh).
// ---------------------------------------------------------------------------
__global__ __launch_bounds__(512) void softs_agg_kernel(
    const float* __restrict__ X, const float* __restrict__ tf,
    const float* __restrict__ P, float* __restrict__ out)
{
    __shared__ float wl[SDIM * KDIM];          // 12.8 KB
    __shared__ float tfl[SDIM];                // 0.8 KB
    __shared__ float invk[KDIM];
    __shared__ float red[6 * 8 * HDIM];        // 48 KB: slot (sq-1)*2+kh
    float* psum = red;                         // alias (dead before red use)

    const int tid = threadIdx.x;
    const int b   = blockIdx.x;

    // ---- phase 1: column softmax over S (exp(-2500)==0 handles the mask) ----
    const float* Pb = P + (long)b * SDIM * KDIM;
    float ps = 0.f;
    #pragma unroll
    for (int t = 0; t < 7; ++t) {
        int i = tid + t * 512;
        if (i < SDIM * KDIM) {
            float e = __expf(Pb[i]);
            wl[i] = e;
            ps += e;
        }
    }
    psum[tid] = ps;
    if (tid < SDIM) tfl[tid] = tf[b * SDIM + tid];
    __syncthreads();

    if (tid < KDIM) {
        float s = 0.f;
        #pragma unroll
        for (int g = 0; g < 32; ++g) s += psum[tid + g * 16];   // 512%16==0
        invk[tid] = 1.f / s;
    }
    __syncthreads();

    #pragma unroll
    for (int t = 0; t < 7; ++t) {
        int i = tid + t * 512;
        if (i < SDIM * KDIM) wl[i] *= tfl[i >> 4] * invk[i & 15];
    }
    __syncthreads();

    // ---- phase 2: out[b,k,h] = sum_s X[b,s,h] * wl[s,k] ----
    const int wv = tid >> 6;
    const int sq = wv >> 1;      // s-quarter: [50*sq, 50*sq+50)
    const int kh = wv & 1;       // k-half: k in [8*kh, 8*kh+8)
    const int ln = tid & 63;     // lane -> h-cols 4*ln..4*ln+3

    f32x4 acc[8];
    #pragma unroll
    for (int j = 0; j < 8; ++j) acc[j] = (f32x4){0.f, 0.f, 0.f, 0.f};

    const f32x4* Xb4 = (const f32x4*)(X + (long)b * SDIM * HDIM);
    const f32x4* wl4 = (const f32x4*)wl;
    const int s0 = sq * 50;
    #pragma unroll 5
    for (int si = 0; si < 50; ++si) {
        int s = s0 + si;
        f32x4 x  = Xb4[s * 64 + ln];             // 1KB coalesced per wave
        f32x4 d0 = wl4[s * 4 + 2 * kh + 0];      // wave-uniform LDS b128
        f32x4 d1 = wl4[s * 4 + 2 * kh + 1];
        #pragma unroll
        for (int j = 0; j < 4; ++j) {
            acc[j]     += x * d0[j];             // k = 8kh + j
            acc[4 + j] += x * d1[j];             // k = 8kh + 4 + j
        }
    }

    // ---- tree reduce over s-quarters: sq>0 deposit, sq==0 sums + stores ----
    if (sq > 0) {
        float* rp = red + (((sq - 1) * 2 + kh) * 8) * HDIM;
        #pragma unroll
        for (int j = 0; j < 8; ++j)
            *(f32x4*)(rp + j * HDIM + 4 * ln) = acc[j];
    }
    __syncthreads();
    if (sq == 0) {
        #pragma unroll
        for (int p = 0; p < 3; ++p) {
            const float* rp = red + ((p * 2 + kh) * 8) * HDIM;
            #pragma unroll
            for (int j = 0; j < 8; ++j)
                acc[j] += *(const f32x4*)(rp + j * HDIM + 4 * ln);
        }
        float* ob = out + (long)b * KDIM * HDIM + kh * 8 * HDIM;
        #pragma unroll
        for (int j = 0; j < 8; ++j)
            *(f32x4*)(ob + j * HDIM + 4 * ln) = acc[j];
    }
}

extern "C" void kernel_launch(void* const* d_in, const int* in_sizes, int n_in,
                              void* d_out, int out_size, void* d_ws, size_t ws_size,
                              hipStream_t stream) {
    (void)in_sizes; (void)n_in; (void)out_size; (void)ws_size;
    const float* X    = (const float*)d_in[0];
    const int*   mask = (const int*)  d_in[1];
    const float* tf   = (const float*)d_in[2];
    const float* W1   = (const float*)d_in[3];
    const float* b1   = (const float*)d_in[4];
    const float* W2   = (const float*)d_in[5];
    const float* b2   = (const float*)d_in[6];
    const float* W3   = (const float*)d_in[7];
    float* out = (float*)d_out;

    char* ws = (char*)d_ws;
    float*  P   = (float*)ws;                          // 102400*16*4 = 6,553,600 B
    __bf16* w1h = (__bf16*)(ws + 6553600);             // 65536 elems each
    __bf16* w1l = w1h + 65536;
    __bf16* w2h = w1l + 65536;
    __bf16* w2l = w2h + 65536;
    __bf16* w3h = w2l + 65536;                         // 4096 elems each
    __bf16* w3l = w3h + 4096;

    pack_all<<<528, 256, 0, stream>>>(W1, W2, W3, w1h, w1l, w2h, w2l, w3h, w3l);
    mlp_softk_mfma<<<NROWS / TM, 512, 0, stream>>>(X, mask, w1h, w1l, b1,
                                                   w2h, w2l, b2, w3h, w3l, P);
    softs_agg_kernel<<<BDIM, 512, 0, stream>>>(X, tf, P, out);
}

// Round 9
// 240.937 us; speedup vs baseline: 2.6710x; 1.0217x over previous
//
#include <hip/hip_runtime.h>
#include <math.h>

#define HDIM 256
#define KDIM 16
#define SDIM 200
#define BDIM 512
#define NROWS (BDIM * SDIM)   // 102400
#define TM 64                 // rows per block (64KB LDS, 2 blk/CU, 8 waves)

typedef _Float16 f16x8 __attribute__((ext_vector_type(8)));
typedef _Float16 f16x4 __attribute__((ext_vector_type(4)));
typedef float    f32x4 __attribute__((ext_vector_type(4)));

// ---------------------------------------------------------------------------
// Pack v14: W1/W2 -> SINGLE f16 fragment layout (2-pass scheme):
//   dst[((k>>3)*N + n)*8 + (k&7)] = f16 of W[k*N + n]
// W3 -> SPLIT f16 hi/lo (logits keep 3-pass precision; cost trivial).
// ---------------------------------------------------------------------------
__global__ __launch_bounds__(256) void pack_all(
    const float* __restrict__ W1, const float* __restrict__ W2,
    const float* __restrict__ W3,
    _Float16* __restrict__ w1, _Float16* __restrict__ w2,
    _Float16* __restrict__ w3h, _Float16* __restrict__ w3l)
{
    int gid = blockIdx.x * 256 + threadIdx.x;
    if (gid < 131072) {
        int sel = gid >> 16;                 // 0: W1, 1: W2
        int e   = gid & 65535;
        const float* src = sel ? W2 : W1;
        _Float16*    dst = sel ? w2 : w1;
        int j  = e & 7;
        int n  = (e >> 3) & 255;
        int kg = e >> 11;
        dst[e] = (_Float16)src[(kg * 8 + j) * 256 + n];
    } else if (gid < 135168) {
        int e  = gid - 131072;
        int j  = e & 7;
        int n  = (e >> 3) & 15;
        int kg = e >> 7;
        float v = W3[(kg * 8 + j) * 16 + n];
        _Float16 h = (_Float16)v;
        w3h[e] = h;
        w3l[e] = (_Float16)(v - (float)h);
    }
}

// ---------------------------------------------------------------------------
// Kernel 1 v14: f16 2-PASS. R8 confirmed the budget: MFMA ~40us (3-pass
// split-bf16 tax), W stream ~22us, VALU ~24us. f16 carries 11 mantissa
// bits, so X split-f16 (eff ~22b) x W single-f16 (2^-11) needs only
// 2 MFMA passes and ONE W stream: MFMA 40->27us, W stream 22->11us.
// W3 stays split f16 (3-pass) to protect logits. Same TM=64 / 8-wave /
// 64KB-LDS / swizzle structure as R8 (both confirmed levers kept).
// Accuracy experiment: predicted absmax ~1e-3 (round-6's 9.77e-4 passed).
// ---------------------------------------------------------------------------
__global__ __launch_bounds__(512) void mlp_softk_mfma(
    const float* __restrict__ X, const int* __restrict__ mask,
    const _Float16* __restrict__ W1f, const float* __restrict__ b1,
    const _Float16* __restrict__ W2f, const float* __restrict__ b2,
    const _Float16* __restrict__ W3h, const _Float16* __restrict__ W3l,
    float* __restrict__ P)
{
    __shared__ _Float16 Ahi[TM * HDIM];   // 32 KB
    __shared__ _Float16 Alo[TM * HDIM];   // 32 KB

    const int tid  = threadIdx.x;
    const int lane = tid & 63;
    const int w    = tid >> 6;      // wave id 0..7: owns cols 32w..32w+31
    const int l15  = lane & 15;
    const int quad = lane >> 4;
    const long r0  = (long)blockIdx.x * TM;

    // ---- stage X tile -> LDS as split f16 (swizzled) ----
    {
        const float4* Xt = (const float4*)(X + r0 * HDIM);
        #pragma unroll
        for (int t = 0; t < (TM * HDIM / 4) / 512; ++t) {
            int v4  = tid + t * 512;
            float4 f = Xt[v4];
            int row = v4 >> 6;            // 64 float4 per row
            int col = (v4 & 63) << 2;
            int kgs = (col >> 3) ^ (row & 31);
            int base = row * HDIM + kgs * 8 + (col & 7);
            _Float16 h0 = (_Float16)f.x, h1 = (_Float16)f.y,
                     h2 = (_Float16)f.z, h3 = (_Float16)f.w;
            f16x4 hv = {h0, h1, h2, h3};
            f16x4 lv = {(_Float16)(f.x - (float)h0), (_Float16)(f.y - (float)h1),
                        (_Float16)(f.z - (float)h2), (_Float16)(f.w - (float)h3)};
            *(f16x4*)(&Ahi[base]) = hv;
            *(f16x4*)(&Alo[base]) = lv;
        }
    }
    __syncthreads();

    f32x4 acc[4][2];

    auto layer = [&](const _Float16* __restrict__ Wf, const float* __restrict__ bias) {
        #pragma unroll
        for (int mt = 0; mt < 4; ++mt)
            #pragma unroll
            for (int nt = 0; nt < 2; ++nt)
                acc[mt][nt] = (f32x4){0.f, 0.f, 0.f, 0.f};

        #pragma unroll
        for (int kc = 0; kc < 8; ++kc) {
            f16x8 bh[2];
            #pragma unroll
            for (int nt = 0; nt < 2; ++nt) {
                int n  = w * 32 + nt * 16 + l15;
                int kg = kc * 4 + quad;
                bh[nt] = *(const f16x8*)(Wf + (kg * HDIM + n) * 8);
            }
            #pragma unroll
            for (int mt = 0; mt < 4; ++mt) {
                int row = mt * 16 + l15;
                int kgs = (kc * 4 + quad) ^ (row & 31);
                f16x8 ah = *(const f16x8*)(&Ahi[row * HDIM + kgs * 8]);
                f16x8 al = *(const f16x8*)(&Alo[row * HDIM + kgs * 8]);
                // SWAPPED: A-operand = W fragment, B-operand = X fragment.
                #pragma unroll
                for (int nt = 0; nt < 2; ++nt) {
                    acc[mt][nt] = __builtin_amdgcn_mfma_f32_16x16x32_f16(
                        bh[nt], ah, acc[mt][nt], 0, 0, 0);
                    acc[mt][nt] = __builtin_amdgcn_mfma_f32_16x16x32_f16(
                        bh[nt], al, acc[mt][nt], 0, 0, 0);
                }
            }
        }
        __syncthreads();   // everyone done reading A before overwrite

        // C layout (swapped): m = mt*16 + (lane&15), n = w*32 + nt*16 + quad*4 + r
        // -> regs r=0..3 are 4 consecutive h-columns: one f16x4 write per array.
        f32x4 bias4[2];
        #pragma unroll
        for (int nt = 0; nt < 2; ++nt)
            bias4[nt] = *(const f32x4*)(bias + w * 32 + nt * 16 + quad * 4);

        #pragma unroll
        for (int mt = 0; mt < 4; ++mt)
            #pragma unroll
            for (int nt = 0; nt < 2; ++nt) {
                int m   = mt * 16 + l15;
                int g   = w * 4 + nt * 2 + (quad >> 1);          // n>>3
                int idx = m * HDIM + (((g ^ (m & 31)) * 8) + (quad & 1) * 4);
                f16x4 hv, lv;
                #pragma unroll
                for (int r = 0; r < 4; ++r) {
                    float v = fmaxf(acc[mt][nt][r] + bias4[nt][r], 0.f);
                    _Float16 h = (_Float16)v;
                    hv[r] = h;
                    lv[r] = (_Float16)(v - (float)h);
                }
                *(f16x4*)(&Ahi[idx]) = hv;
                *(f16x4*)(&Alo[idx]) = lv;
            }
        __syncthreads();
    };

    layer(W1f, b1);
    layer(W2f, b2);

    // ---- logits: waves 0..3 each handle one 16-row m-tile (TM=64) ----
    // W3 split f16, 3-pass (drop al x bl): eff ~2^-22 -- protects softmax.
    if (w < 4) {
        f32x4 lg = {0.f, 0.f, 0.f, 0.f};
        #pragma unroll
        for (int kc = 0; kc < 8; ++kc) {
            int row = w * 16 + l15;
            int kg  = kc * 4 + quad;
            int kgs = kg ^ (row & 31);
            f16x8 ah = *(const f16x8*)(&Ahi[row * HDIM + kgs * 8]);
            f16x8 al = *(const f16x8*)(&Alo[row * HDIM + kgs * 8]);
            f16x8 bh = *(const f16x8*)(W3h + (kg * KDIM + l15) * 8);
            f16x8 bl = *(const f16x8*)(W3l + (kg * KDIM + l15) * 8);
            lg = __builtin_amdgcn_mfma_f32_16x16x32_f16(ah, bh, lg, 0, 0, 0);
            lg = __builtin_amdgcn_mfma_f32_16x16x32_f16(al, bh, lg, 0, 0, 0);
            lg = __builtin_amdgcn_mfma_f32_16x16x32_f16(ah, bl, lg, 0, 0, 0);
        }

        // softmax over k: 16 lanes of a quad-group hold the 16 cols of a row
        #pragma unroll
        for (int r = 0; r < 4; ++r) {
            float v  = lg[r];
            float mx = v;
            mx = fmaxf(mx, __shfl_xor(mx, 1));
            mx = fmaxf(mx, __shfl_xor(mx, 2));
            mx = fmaxf(mx, __shfl_xor(mx, 4));
            mx = fmaxf(mx, __shfl_xor(mx, 8));
            float e = __expf(v - mx);
            float s = e;
            s += __shfl_xor(s, 1);
            s += __shfl_xor(s, 2);
            s += __shfl_xor(s, 4);
            s += __shfl_xor(s, 8);
            int grow = (int)r0 + w * 16 + quad * 4 + r;
            int mv   = mask[grow];
            float ov = mv ? (e / s) * 0.25f : -2500.0f;   // (-10000)/sqrt(16)
            P[(long)grow * KDIM + l15] = ov;
        }
    }
}

// ---------------------------------------------------------------------------
// Kernel 2 (UNCHANGED): 512 threads = 8 waves = (s-quarter sq, k-half kh).
// ---------------------------------------------------------------------------
__global__ __launch_bounds__(512) void softs_agg_kernel(
    const float* __restrict__ X, const float* __restrict__ tf,
    const float* __restrict__ P, float* __restrict__ out)
{
    __shared__ float wl[SDIM * KDIM];          // 12.8 KB
    __shared__ float tfl[SDIM];                // 0.8 KB
    __shared__ float invk[KDIM];
    __shared__ float red[6 * 8 * HDIM];        // 48 KB: slot (sq-1)*2+kh
    float* psum = red;                         // alias (dead before red use)

    const int tid = threadIdx.x;
    const int b   = blockIdx.x;

    // ---- phase 1: column softmax over S (exp(-2500)==0 handles the mask) ----
    const float* Pb = P + (long)b * SDIM * KDIM;
    float ps = 0.f;
    #pragma unroll
    for (int t = 0; t < 7; ++t) {
        int i = tid + t * 512;
        if (i < SDIM * KDIM) {
            float e = __expf(Pb[i]);
            wl[i] = e;
            ps += e;
        }
    }
    psum[tid] = ps;
    if (tid < SDIM) tfl[tid] = tf[b * SDIM + tid];
    __syncthreads();

    if (tid < KDIM) {
        float s = 0.f;
        #pragma unroll
        for (int g = 0; g < 32; ++g) s += psum[tid + g * 16];   // 512%16==0
        invk[tid] = 1.f / s;
    }
    __syncthreads();

    #pragma unroll
    for (int t = 0; t < 7; ++t) {
        int i = tid + t * 512;
        if (i < SDIM * KDIM) wl[i] *= tfl[i >> 4] * invk[i & 15];
    }
    __syncthreads();

    // ---- phase 2: out[b,k,h] = sum_s X[b,s,h] * wl[s,k] ----
    const int wv = tid >> 6;
    const int sq = wv >> 1;      // s-quarter: [50*sq, 50*sq+50)
    const int kh = wv & 1;       // k-half: k in [8*kh, 8*kh+8)
    const int ln = tid & 63;     // lane -> h-cols 4*ln..4*ln+3

    f32x4 acc[8];
    #pragma unroll
    for (int j = 0; j < 8; ++j) acc[j] = (f32x4){0.f, 0.f, 0.f, 0.f};

    const f32x4* Xb4 = (const f32x4*)(X + (long)b * SDIM * HDIM);
    const f32x4* wl4 = (const f32x4*)wl;
    const int s0 = sq * 50;
    #pragma unroll 5
    for (int si = 0; si < 50; ++si) {
        int s = s0 + si;
        f32x4 x  = Xb4[s * 64 + ln];             // 1KB coalesced per wave
        f32x4 d0 = wl4[s * 4 + 2 * kh + 0];      // wave-uniform LDS b128
        f32x4 d1 = wl4[s * 4 + 2 * kh + 1];
        #pragma unroll
        for (int j = 0; j < 4; ++j) {
            acc[j]     += x * d0[j];             // k = 8kh + j
            acc[4 + j] += x * d1[j];             // k = 8kh + 4 + j
        }
    }

    // ---- tree reduce over s-quarters: sq>0 deposit, sq==0 sums + stores ----
    if (sq > 0) {
        float* rp = red + (((sq - 1) * 2 + kh) * 8) * HDIM;
        #pragma unroll
        for (int j = 0; j < 8; ++j)
            *(f32x4*)(rp + j * HDIM + 4 * ln) = acc[j];
    }
    __syncthreads();
    if (sq == 0) {
        #pragma unroll
        for (int p = 0; p < 3; ++p) {
            const float* rp = red + ((p * 2 + kh) * 8) * HDIM;
            #pragma unroll
            for (int j = 0; j < 8; ++j)
                acc[j] += *(const f32x4*)(rp + j * HDIM + 4 * ln);
        }
        float* ob = out + (long)b * KDIM * HDIM + kh * 8 * HDIM;
        #pragma unroll
        for (int j = 0; j < 8; ++j)
            *(f32x4*)(ob + j * HDIM + 4 * ln) = acc[j];
    }
}

extern "C" void kernel_launch(void* const* d_in, const int* in_sizes, int n_in,
                              void* d_out, int out_size, void* d_ws, size_t ws_size,
                              hipStream_t stream) {
    (void)in_sizes; (void)n_in; (void)out_size; (void)ws_size;
    const float* X    = (const float*)d_in[0];
    const int*   mask = (const int*)  d_in[1];
    const float* tf   = (const float*)d_in[2];
    const float* W1   = (const float*)d_in[3];
    const float* b1   = (const float*)d_in[4];
    const float* W2   = (const float*)d_in[5];
    const float* b2   = (const float*)d_in[6];
    const float* W3   = (const float*)d_in[7];
    float* out = (float*)d_out;

    char* ws = (char*)d_ws;
    float*    P   = (float*)ws;                        // 102400*16*4 = 6,553,600 B
    _Float16* w1  = (_Float16*)(ws + 6553600);         // 65536 elems each (single)
    _Float16* w2  = w1 + 65536;
    _Float16* w3h = w2 + 65536;                        // 4096 elems each (split)
    _Float16* w3l = w3h + 4096;

    pack_all<<<528, 256, 0, stream>>>(W1, W2, W3, w1, w2, w3h, w3l);
    mlp_softk_mfma<<<NROWS / TM, 512, 0, stream>>>(X, mask, w1, b1,
                                                   w2, b2, w3h, w3l, P);
    softs_agg_kernel<<<BDIM, 512, 0, stream>>>(X, tf, P, out);
}